// Round 10
// baseline (1796.165 us; speedup 1.0000x reference)
//
#include <hip/hip_runtime.h>

// ---------------------------------------------------------------------------
// Llama4TextExperts: per-expert  out = (up * silu(gate)) @ W2
// E=8, T=8192 (1024/expert), H=2048, I=4096, fp32 in/out, bf16 MFMA compute.
// R10: balanced phases — B staging spread 1 unit/phase (static j), B loads
//      4+4 at P0/P1, A stages 2+2 at P1/P2; single vmcnt(4)@P0 (B regs) +
//      vmcnt(12)@P3 (proves A(t+1) BEFORE the barrier -> cross-wave safe).
//      Epilogues via LDS roundtrip -> coalesced 16B stores (fixes R9's
//      scattered-store regression). B LDS patterns = R9's measured-0-conflict.
// ---------------------------------------------------------------------------

#define E_   8
#define H_   2048
#define I_   4096
#define T_   8192
#define TPE  1024

typedef __bf16 bf16x8 __attribute__((ext_vector_type(8)));
typedef float  f32x4  __attribute__((ext_vector_type(4)));

__device__ __forceinline__ unsigned short f2bf(float f) {
  union { float f; unsigned int u; } v; v.f = f;
  unsigned int u = v.u;
  u += 0x7FFFu + ((u >> 16) & 1u);   // RNE
  return (unsigned short)(u >> 16);
}

__device__ __forceinline__ void async16(const void* g, void* l) {
  __builtin_amdgcn_global_load_lds(
      (__attribute__((address_space(1))) void*)(g),
      (__attribute__((address_space(3))) void*)(l), 16, 0, 0);
}

#define SB0()      __builtin_amdgcn_sched_barrier(0)
#define BAR()      __builtin_amdgcn_s_barrier()
#define WAITLGKM() asm volatile("s_waitcnt lgkmcnt(0)" ::: "memory")
#define WAITVM(n)  asm volatile("s_waitcnt vmcnt(" #n ")" ::: "memory")

// ---------------------------------------------------------------------------
__global__ void convert_bf16(const float* __restrict__ src,
                             unsigned short* __restrict__ dst, long n) {
  long i = ((long)blockIdx.x * blockDim.x + threadIdx.x) * 4;
  const long stride = (long)gridDim.x * blockDim.x * 4;
  for (; i < n; i += stride) {
    const float4 v = *(const float4*)&src[i];
    ushort4 o;
    o.x = f2bf(v.x); o.y = f2bf(v.y); o.z = f2bf(v.z); o.w = f2bf(v.w);
    *(ushort4*)&dst[i] = o;
  }
}

// ---------------------------------------------------------------------------
// 256x256x64 4-phase GEMM, 8 waves (2Mx4N). LDS 128KB: A[2][256][64] bf16 +
// B[2][256][64] bf16. A via global_load_lds (pre-swizzled src). B fp32 via
// f4 loads along N (lane owns stride-64 rows {64j+lane} = contiguous cols
// cbase+j), reg transpose, ds_write at slot wave^(lane&7)  [R9: 0 conflicts].
// Per tile t:
//  P0: vmcnt(4) [B(t+1) regs]; write j0; read a-q0(8)+b0(4); f4 x4 B(t+2);
//      BAR lgkm MFMA(aq0*b0) BAR
//  P1: write j1; read b1(4); stage A(t+2)q0; f4 x4; BAR lgkm MFMA(aq0*b1) BAR
//  P2: write j2; read a-q1(8); stage A(t+2)q1; BAR lgkm MFMA(aq1*b1) BAR
//  P3: write j3; vmcnt(12) [A(t+1) proven pre-barrier]; BAR lgkm
//      MFMA(aq1*b0) BAR
// Steady FIFO carry-in [B(t+1)x8, A(t+1)x4]; both waits verified exact.
// ---------------------------------------------------------------------------
template <int K, int NBN, int LDB, bool SILU>
__global__ __launch_bounds__(512, 2)
void gemm_fused(const unsigned short* __restrict__ Aall,
                const float* __restrict__ Ball,
                void* __restrict__ Cout,
                long sA, long sB, long sC) {
  extern __shared__ char smem[];
  constexpr int NT = K / 64;
  static_assert(NT % 2 == 0, "NT must be even for the x2 unroll");

  const int tid  = threadIdx.x;
  const int wave = tid >> 6;
  const int lane = tid & 63;
  const int lr   = lane & 15;
  const int lq   = lane >> 4;
  const int wid_m = wave >> 2;     // 0..1
  const int wid_n = wave & 3;      // 0..3

  // T1: bijective XCD swizzle (gridDim.x % 8 == 0), mb innermost.
  const int nwg = gridDim.x;
  const int bid = blockIdx.x;
  const int wg  = (bid & 7) * (nwg >> 3) + (bid >> 3);
  const int mb  = wg & 3;
  const int tmp = wg >> 2;
  const int nb  = tmp % NBN;
  const int e   = tmp / NBN;

  const unsigned short* A = Aall + (long)e * sA + (long)(mb * 256) * K;
  const float*          B = Ball + (long)e * sB;

  // ---- A staging (global_load_lds, pre-swizzled source) ------------------
  const int stl  = tid >> 3;                      // 0..63
  const int scol = ((tid & 7) ^ (stl & 7)) * 8;   // swizzled src elem col

  auto stageA = [&](int bi, int q, int kt) {
    const long col = (long)kt * 64 + scol;
    char* l0 = smem + bi * 32768 + q * 16384 + wave * 1024;
    async16(A + (long)(q * 64 + stl) * K + col,        l0);
    async16(A + (long)(128 + q * 64 + stl) * K + col,  l0 + 8192);
  };

  // ---- B: lane owns storage rows {64j+lane} = global cols cbase+j --------
  int cbase;
  if (SILU) {
    cbase = nb * 128 + (lane >> 5) * 64 + (lane & 15) * 4
          + (((lane >> 4) & 1) ? I_ : 0);
  } else {
    cbase = nb * 256 + lane * 4;
  }
  const float* Bq = B + cbase;

  f32x4 bvA[8], bvB[8];

  // load f4 half h (i = 4h..4h+3); h passed as literal
  auto LOADB4 = [&](auto& bv, int kt, int h) {
    const long kbase = (long)kt * 64 + wave * 8 + h * 4;
#pragma unroll
    for (int i = 0; i < 4; ++i)
      bv[4 * h + i] = *(const f32x4*)&Bq[(kbase + i) * (long)LDB];
  };
  // write one unit j (literal at call sites): row 64j+lane, slot wave^(lane&7)
  auto WRITEB1 = [&](int bo, auto& bv, int j) {
    char* LBw = smem + 65536 + bo * 32768 + ((wave ^ (lane & 7)) * 16);
    bf16x8 pk;
#pragma unroll
    for (int i = 0; i < 8; ++i) pk[i] = (__bf16)bv[i][j];
    *(bf16x8*)(LBw + (64 * j + lane) * 128) = pk;
  };

  // fragment-read swizzled slot offsets (key = lr&7 for both A and B)
  const int ax0 = ((0 + lq) ^ (lr & 7)) * 16;    // k 0..31
  const int ax1 = ((4 + lq) ^ (lr & 7)) * 16;    // k 32..63

  f32x4 acc[8][4];
#pragma unroll
  for (int m = 0; m < 8; ++m)
#pragma unroll
    for (int n = 0; n < 4; ++n) acc[m][n] = (f32x4)0.0f;

  // ---------------- prologue --------------------------------------------
  const int t1p = (NT > 1) ? 1 : 0;
  LOADB4(bvA, 0, 0); LOADB4(bvA, 0, 1);   // f4 x8  B(0)
  stageA(0, 0, 0); stageA(0, 1, 0);       // a16 x4 A(0)
  SB0();
  WAITVM(4); SB0();                       // retire B(0)x8 (leaves A(0)x4)
  WRITEB1(0, bvA, 0); WRITEB1(0, bvA, 1);
  WRITEB1(0, bvA, 2); WRITEB1(0, bvA, 3);
  LOADB4(bvB, t1p, 0); LOADB4(bvB, t1p, 1);  // f4 x8 B(1)
  stageA(1, 0, t1p); stageA(1, 1, t1p);      // a16 x4 A(1)
  SB0();
  WAITVM(12); SB0();                      // retire A(0)x4; leaves [B(1)8,A(1)4]
  WAITLGKM(); SB0();                      // publish B(0) writes
  BAR();

  // ---------------- tile body (bvW holds B(t+1); bvL gets B(t+2)) --------
  auto body = [&](int t, auto& bvW, auto& bvL) {
    const int cur = t & 1;
    const int bo  = cur ^ 1;
    const char* LA = smem + cur * 32768;
    const char* LB = smem + 65536 + cur * 32768;
    const int t2v = (t + 2 < NT) ? t + 2 : NT - 1;

    bf16x8 a[4][2], b0[2][2], b1[2][2];

    // ---- P0: vmcnt(4); write j0; read a-q0 + b0; issue f4 h0 -----------
    WAITVM(4); SB0();          // retires B(t+1)x8; leaves A(t+1)x4
    WRITEB1(bo, bvW, 0);
#pragma unroll
    for (int mf = 0; mf < 4; ++mf) {
      const int st = wid_m * 64 + mf * 16 + lr;
      a[mf][0] = *(const bf16x8*)(LA + st * 128 + ax0);
      a[mf][1] = *(const bf16x8*)(LA + st * 128 + ax1);
    }
#pragma unroll
    for (int nf = 0; nf < 2; ++nf) {
      const int st = wid_n * 32 + nf * 16 + lr;
      b0[nf][0] = *(const bf16x8*)(LB + st * 128 + ax0);
      b0[nf][1] = *(const bf16x8*)(LB + st * 128 + ax1);
    }
    LOADB4(bvL, t2v, 0);
    SB0();
    BAR();
    WAITLGKM(); SB0();
    __builtin_amdgcn_s_setprio(1);
#pragma unroll
    for (int mf = 0; mf < 4; ++mf)
#pragma unroll
      for (int nf = 0; nf < 2; ++nf) {
        acc[mf][nf] = __builtin_amdgcn_mfma_f32_16x16x32_bf16(a[mf][0], b0[nf][0], acc[mf][nf], 0, 0, 0);
        acc[mf][nf] = __builtin_amdgcn_mfma_f32_16x16x32_bf16(a[mf][1], b0[nf][1], acc[mf][nf], 0, 0, 0);
      }
    __builtin_amdgcn_s_setprio(0);
    BAR();

    // ---- P1: write j1; read b1; stage A(t+2)q0; issue f4 h1 ------------
    WRITEB1(bo, bvW, 1);
#pragma unroll
    for (int nf = 0; nf < 2; ++nf) {
      const int st = 128 + wid_n * 32 + nf * 16 + lr;
      b1[nf][0] = *(const bf16x8*)(LB + st * 128 + ax0);
      b1[nf][1] = *(const bf16x8*)(LB + st * 128 + ax1);
    }
    stageA(cur, 0, t2v);
    LOADB4(bvL, t2v, 1);
    SB0();
    BAR();
    WAITLGKM(); SB0();
    __builtin_amdgcn_s_setprio(1);
#pragma unroll
    for (int mf = 0; mf < 4; ++mf)
#pragma unroll
      for (int nf = 0; nf < 2; ++nf) {
        acc[mf][2 + nf] = __builtin_amdgcn_mfma_f32_16x16x32_bf16(a[mf][0], b1[nf][0], acc[mf][2 + nf], 0, 0, 0);
        acc[mf][2 + nf] = __builtin_amdgcn_mfma_f32_16x16x32_bf16(a[mf][1], b1[nf][1], acc[mf][2 + nf], 0, 0, 0);
      }
    __builtin_amdgcn_s_setprio(0);
    BAR();

    // ---- P2: write j2; read a-q1; stage A(t+2)q1 -----------------------
    WRITEB1(bo, bvW, 2);
#pragma unroll
    for (int mf = 0; mf < 4; ++mf) {
      const int st = 128 + wid_m * 64 + mf * 16 + lr;
      a[mf][0] = *(const bf16x8*)(LA + st * 128 + ax0);
      a[mf][1] = *(const bf16x8*)(LA + st * 128 + ax1);
    }
    stageA(cur, 1, t2v);
    SB0();
    BAR();
    WAITLGKM(); SB0();
    __builtin_amdgcn_s_setprio(1);
#pragma unroll
    for (int mf = 0; mf < 4; ++mf)
#pragma unroll
      for (int nf = 0; nf < 2; ++nf) {
        acc[4 + mf][2 + nf] = __builtin_amdgcn_mfma_f32_16x16x32_bf16(a[mf][0], b1[nf][0], acc[4 + mf][2 + nf], 0, 0, 0);
        acc[4 + mf][2 + nf] = __builtin_amdgcn_mfma_f32_16x16x32_bf16(a[mf][1], b1[nf][1], acc[4 + mf][2 + nf], 0, 0, 0);
      }
    __builtin_amdgcn_s_setprio(0);
    BAR();

    // ---- P3: write j3; vmcnt(12) proves A(t+1) pre-barrier -------------
    WRITEB1(bo, bvW, 3);
    SB0();
    WAITVM(12); SB0();         // retires A(t+1)x4 (leaves [B(t+2)8,A(t+2)4])
    BAR();
    WAITLGKM(); SB0();
    __builtin_amdgcn_s_setprio(1);
#pragma unroll
    for (int mf = 0; mf < 4; ++mf)
#pragma unroll
      for (int nf = 0; nf < 2; ++nf) {
        acc[4 + mf][nf] = __builtin_amdgcn_mfma_f32_16x16x32_bf16(a[mf][0], b0[nf][0], acc[4 + mf][nf], 0, 0, 0);
        acc[4 + mf][nf] = __builtin_amdgcn_mfma_f32_16x16x32_bf16(a[mf][1], b0[nf][1], acc[4 + mf][nf], 0, 0, 0);
      }
    __builtin_amdgcn_s_setprio(0);
    BAR();
  };

#pragma unroll 1
  for (int tt = 0; tt < NT; tt += 2) {
    body(tt,     bvB, bvA);    // even t: write B(t+1) from bvB, load into bvA
    body(tt + 1, bvA, bvB);    // odd  t: write from bvA, load into bvB
  }

  WAITVM(0);                   // trailing DMAs must land before LDS reuse

  // ---------------- epilogue via LDS roundtrip (coalesced stores) --------
  // C/D frag: col=lane&15, row=(lane>>4)*4+r. B-col permutation absorbed
  // into LDS placement; global stores are contiguous 16B.
  if (SILU) {
    unsigned short* Cc = (unsigned short*)Cout + (long)e * sC;
    BAR();
#pragma unroll
    for (int mf = 0; mf < 8; ++mf)
#pragma unroll
      for (int p = 0; p < 2; ++p)
#pragma unroll
        for (int rr = 0; rr < 4; ++rr) {
          const int row = wid_m * 128 + mf * 16 + lq * 4 + rr;          // 0..255
          const int col = (wid_n & 1) * 64 + lr * 4 + 2 * p + (wid_n >> 1); // 0..127
          const float g = acc[mf][p * 2][rr];
          const float u = acc[mf][p * 2 + 1][rr];
          *(unsigned short*)(smem + ((long)row * 128 + col) * 2) =
              f2bf(u * (g / (1.0f + __expf(-g))));
        }
    BAR();
#pragma unroll
    for (int pass = 0; pass < 8; ++pass) {
      const int row = pass * 32 + (tid >> 4);
      const int c8  = (tid & 15) * 8;
      const f32x4 v = *(const f32x4*)(smem + ((long)row * 128 + c8) * 2);
      *(f32x4*)((char*)&Cc[(long)(mb * 256 + row) * I_ + nb * 128 + c8]) = v;
    }
  } else {
    float* Cc = (float*)Cout + (long)e * sC;
#pragma unroll 1
    for (int h = 0; h < 2; ++h) {
      BAR();
      if (wid_m == h) {
#pragma unroll
        for (int mf = 0; mf < 8; ++mf)
#pragma unroll
          for (int q = 0; q < 4; ++q)
#pragma unroll
            for (int rr = 0; rr < 4; ++rr) {
              const int row = mf * 16 + lq * 4 + rr;                    // 0..127
              const int lp  = (wid_n & 1) * 32 + (q & 1) * 16 + lr;
              const int col = lp * 4 + (q >> 1) * 2 + (wid_n >> 1);     // 0..255
              *(float*)(smem + ((long)row * 256 + col) * 4) = acc[mf][q][rr];
            }
      }
      BAR();
#pragma unroll
      for (int pass = 0; pass < 16; ++pass) {
        const int row = pass * 8 + (tid >> 6);
        const int c4  = (tid & 63) * 4;
        const f32x4 v = *(const f32x4*)(smem + ((long)row * 256 + c4) * 4);
        *(f32x4*)&Cc[(long)(mb * 256 + h * 128 + row) * H_ + nb * 256 + c4] = v;
      }
    }
  }
}

// ---------------------------------------------------------------------------
extern "C" void kernel_launch(void* const* d_in, const int* in_sizes, int n_in,
                              void* d_out, int out_size, void* d_ws, size_t ws_size,
                              hipStream_t stream) {
  const float* hs = (const float*)d_in[0];   // (8192, 2048)
  const float* w1 = (const float*)d_in[1];   // (8, 2048, 8192)
  const float* w2 = (const float*)d_in[2];   // (8, 4096, 2048)
  float* out = (float*)d_out;                // (8192, 2048) fp32
  char* ws = (char*)d_ws;

  const long HB_B  = (long)T_ * H_ * 2;      // 32 MiB hidden bf16
  const long ACT_B = (long)T_ * I_ * 2;      // 64 MiB acted bf16
  if (ws_size < (size_t)(HB_B + ACT_B)) return;

  unsigned short* hiddenB = (unsigned short*)(ws);
  unsigned short* acted   = (unsigned short*)(ws + HB_B);

  hipLaunchKernelGGL(convert_bf16, dim3(2048), dim3(256), 0, stream,
                     hs, hiddenB, (long)T_ * H_);

  // gemm1+SiLU: A=hiddenB (TPE,H), B=W1 (H,2I) fp32 direct -> acted bf16
  hipLaunchKernelGGL((gemm_fused<H_, 32, 2 * I_, true>),
                     dim3(1024), dim3(512), 131072, stream,
                     hiddenB, w1, acted,
                     (long)TPE * H_, (long)H_ * 2 * I_, (long)TPE * I_);

  // gemm2: A=acted (TPE,I), B=W2 (I,H) fp32 direct -> out fp32
  hipLaunchKernelGGL((gemm_fused<I_, 8, H_, false>),
                     dim3(256), dim3(512), 131072, stream,
                     acted, w2, out,
                     (long)TPE * I_, (long)I_ * H_, (long)TPE * H_);
}

// Round 11
// 552.100 us; speedup vs baseline: 3.2533x; 3.2533x over previous
//
#include <hip/hip_runtime.h>

// ---------------------------------------------------------------------------
// Llama4TextExperts: per-expert  out = (up * silu(gate)) @ W2
// E=8, T=8192 (1024/expert), H=2048, I=4096, fp32 in/out, bf16 MFMA compute.
// R11: R5's verified fused-fp32-B GEMM used for BOTH matmuls in plain form.
//      gemm1 = plain 256^2 GEMM over 2I cols -> gate_up bf16 (tests the
//      "SILU dual-region B-geometry is the drag" hypothesis: gemm2 ran
//      1.07 PF with this exact code; gemm1+SILU only 0.66 PF).
//      SiLU applied by a separate vectorized elementwise kernel.
// ---------------------------------------------------------------------------

#define E_   8
#define H_   2048
#define I_   4096
#define T_   8192
#define TPE  1024

typedef __bf16 bf16x8 __attribute__((ext_vector_type(8)));
typedef float  f32x4  __attribute__((ext_vector_type(4)));
typedef unsigned short u16x8 __attribute__((ext_vector_type(8)));

__device__ __forceinline__ unsigned short f2bf(float f) {
  union { float f; unsigned int u; } v; v.f = f;
  unsigned int u = v.u;
  u += 0x7FFFu + ((u >> 16) & 1u);   // RNE
  return (unsigned short)(u >> 16);
}

__device__ __forceinline__ void async16(const void* g, void* l) {
  __builtin_amdgcn_global_load_lds(
      (__attribute__((address_space(1))) void*)(g),
      (__attribute__((address_space(3))) void*)(l), 16, 0, 0);
}

#define SB0()      __builtin_amdgcn_sched_barrier(0)
#define BAR()      __builtin_amdgcn_s_barrier()
#define WAITLGKM() asm volatile("s_waitcnt lgkmcnt(0)" ::: "memory")
#define WAITVM(n)  asm volatile("s_waitcnt vmcnt(" #n ")" ::: "memory")

// ---------------------------------------------------------------------------
__global__ void convert_bf16(const float* __restrict__ src,
                             unsigned short* __restrict__ dst, long n) {
  long i = ((long)blockIdx.x * blockDim.x + threadIdx.x) * 4;
  const long stride = (long)gridDim.x * blockDim.x * 4;
  for (; i < n; i += stride) {
    const float4 v = *(const float4*)&src[i];
    ushort4 o;
    o.x = f2bf(v.x); o.y = f2bf(v.y); o.z = f2bf(v.z); o.w = f2bf(v.w);
    *(ushort4*)&dst[i] = o;
  }
}

// acted = up * silu(gate); gate_up rows of 8192 (gate 0..4095, up 4096..).
__global__ void silu_mul(const unsigned short* __restrict__ gu,
                         unsigned short* __restrict__ acted, long nGroups) {
  long idx = (long)blockIdx.x * blockDim.x + threadIdx.x;
  const long stride = (long)gridDim.x * blockDim.x;
  for (; idx < nGroups; idx += stride) {
    const long r = idx >> 9;            // token row (512 groups x 8 = 4096)
    const long c = (idx & 511) << 3;    // col within I
    const u16x8 g8 = *(const u16x8*)&gu[r * 8192 + c];
    const u16x8 u8 = *(const u16x8*)&gu[r * 8192 + 4096 + c];
    u16x8 o;
#pragma unroll
    for (int i = 0; i < 8; ++i) {
      union { unsigned int u; float f; } gg, uu;
      gg.u = (unsigned int)g8[i] << 16;
      uu.u = (unsigned int)u8[i] << 16;
      const float s = uu.f * (gg.f / (1.0f + __expf(-gg.f)));
      o[i] = f2bf(s);
    }
    *(u16x8*)&acted[r * 4096 + c] = o;
  }
}

// ---------------------------------------------------------------------------
// 256x256x64 8-phase plain GEMM (R5-verified structure, SILU path removed).
// A: bf16 (M,K) via global_load_lds (linear dest, pre-swizzled source,
// row-XOR &7 swizzle). B: fp32 (K,N), per-thread float4 loads along N (lane
// owns 4 contiguous cols = storage rows 4*lane..+3; wave = k-octet), reg
// transpose -> bf16x8 -> ds_write_b128 at slot = ko^((st>>2)&7).
// vmcnt ledger (per-thread/wave issue per tile):
//   P1: A q0(t+2) [2 a16] | P2: vmcnt(4) -> writeB(t+1), issue B(t+2) [8 f4]
//   P3: A q1(t+2) [2 a16], vmcnt(12)
// LDS 128KB: A[2][256][64] bf16 + B[2][256][64] bf16.
// OUTBF selects bf16 vs f32 output; LDC = output row stride.
// ---------------------------------------------------------------------------
template <int K, int NBN, int LDB, int LDC, bool OUTBF>
__global__ __launch_bounds__(512, 2)
void gemm_fused(const unsigned short* __restrict__ Aall,
                const float* __restrict__ Ball,
                void* __restrict__ Cout,
                long sA, long sB, long sC) {
  extern __shared__ char smem[];
  constexpr int NT = K / 64;

  const int tid  = threadIdx.x;
  const int wave = tid >> 6;
  const int lane = tid & 63;
  const int lr   = lane & 15;
  const int lq   = lane >> 4;
  const int wid_m = wave >> 2;     // 0..1
  const int wid_n = wave & 3;      // 0..3

  // T1: bijective XCD swizzle (gridDim.x % 8 == 0), mb innermost.
  const int nwg = gridDim.x;
  const int bid = blockIdx.x;
  const int wg  = (bid & 7) * (nwg >> 3) + (bid >> 3);
  const int mb  = wg & 3;
  const int tmp = wg >> 2;
  const int nb  = tmp % NBN;
  const int e   = tmp / NBN;

  const unsigned short* A = Aall + (long)e * sA + (long)(mb * 256) * K;
  const float*          B = Ball + (long)e * sB;

  // ---- A staging (global_load_lds, pre-swizzled source) ------------------
  const int stl  = tid >> 3;                      // 0..63
  const int scol = ((tid & 7) ^ (stl & 7)) * 8;   // swizzled src elem col

  auto stageA = [&](int bi, int q, int kt) {
    const long col = (long)kt * 64 + scol;
    char* l0 = smem + bi * 32768 + q * 16384 + wave * 1024;
    async16(A + (long)(q * 64 + stl) * K + col,        l0);
    async16(A + (long)(128 + q * 64 + stl) * K + col,  l0 + 8192);
  };

  // ---- B: lane owns storage rows 4*lane..4*lane+3 (contiguous global cols),
  //         wave owns k-octet. 8 float4 loads per tile.
  int colq;   // global col of storage row st = 4*lane (quad is contiguous)
  {
    const int st = 4 * lane;
    const int b  = st >> 7;
    const int r  = st & 127;
    const int w  = r >> 5;
    const int nf = (r >> 4) & 1;
    const int l4 = st & 15;
    colq = nb * 256 + w * 64 + (b * 2 + nf) * 16 + l4;
  }
  const float* Bq = B + colq;

  f32x4 bv[8];
  auto LOADB = [&](int kt) {
    const long kbase = (long)kt * 64 + wave * 8;
#pragma unroll
    for (int i = 0; i < 8; ++i)
      bv[i] = *(const f32x4*)&Bq[(kbase + i) * (long)LDB];
  };
  auto WRITEB = [&](int bo) {
    char* LBw = smem + 65536 + bo * 32768;
    const int slot = wave ^ (lane & 7);           // (st>>2)&7 == lane&7
#pragma unroll
    for (int j = 0; j < 4; ++j) {
      bf16x8 pk;
#pragma unroll
      for (int i = 0; i < 8; ++i) pk[i] = (__bf16)bv[i][j];
      const int st = 4 * lane + j;
      *(bf16x8*)(LBw + st * 128 + slot * 16) = pk;
    }
  };

  // fragment-read swizzled slot offsets
  const int axA0 = ((0 + lq) ^ (lr & 7)) * 16;    // A: k 0..31
  const int axA1 = ((4 + lq) ^ (lr & 7)) * 16;    // A: k 32..63
  const int bxn[2] = { (lr >> 2), 4 + (lr >> 2) };  // B row-quad XOR per nf

  f32x4 acc[8][4];
#pragma unroll
  for (int m = 0; m < 8; ++m)
#pragma unroll
    for (int n = 0; n < 4; ++n) acc[m][n] = (f32x4)0.0f;

  // ---------------- prologue --------------------------------------------
  const int t1p = (NT > 1) ? 1 : 0;
  LOADB(0);                    // 8 f4  (B(0))
  stageA(0, 0, 0);             // 2 a16
  stageA(0, 1, 0);             // 2 a16
  SB0();
  WAITVM(4); SB0();            // B(0) done (leaves A(0) 4)
  WRITEB(0);
  WAITLGKM(); SB0();           // publish B(0); free bv (WAR)
  stageA(1, 0, t1p); SB0();    // 2  A(1)q0
  LOADB(t1p); SB0();           // 8  B(1)
  stageA(1, 1, t1p); SB0();    // 2  A(1)q1
  WAITVM(12); SB0();           // drain A(0); leaves [2,8,2]
  BAR();

#pragma unroll 1
  for (int t = 0; t < NT; ++t) {
    const int cur = t & 1;
    const int bo  = cur ^ 1;
    const char* LA = smem + cur * 32768;
    const char* LB = smem + 65536 + cur * 32768;
    const int t2v = (t + 2 < NT) ? t + 2 : NT - 1;

    bf16x8 a[4][2], b0[2][2], b1[2][2];

    // ---- P0: read a(q0)+b0; no VMEM ------------------------------------
#pragma unroll
    for (int mf = 0; mf < 4; ++mf) {
      const int st = wid_m * 64 + mf * 16 + lr;
      a[mf][0] = *(const bf16x8*)(LA + st * 128 + axA0);
      a[mf][1] = *(const bf16x8*)(LA + st * 128 + axA1);
    }
#pragma unroll
    for (int nf = 0; nf < 2; ++nf) {
      const int st = wid_n * 32 + nf * 16 + lr;
      b0[nf][0] = *(const bf16x8*)(LB + st * 128 + ((0 + lq) ^ bxn[nf]) * 16);
      b0[nf][1] = *(const bf16x8*)(LB + st * 128 + ((4 + lq) ^ bxn[nf]) * 16);
    }
    SB0();
    BAR();
    WAITLGKM(); SB0();
    __builtin_amdgcn_s_setprio(1);
#pragma unroll
    for (int mf = 0; mf < 4; ++mf)
#pragma unroll
      for (int nf = 0; nf < 2; ++nf) {
        acc[mf][nf] = __builtin_amdgcn_mfma_f32_16x16x32_bf16(a[mf][0], b0[nf][0], acc[mf][nf], 0, 0, 0);
        acc[mf][nf] = __builtin_amdgcn_mfma_f32_16x16x32_bf16(a[mf][1], b0[nf][1], acc[mf][nf], 0, 0, 0);
      }
    __builtin_amdgcn_s_setprio(0);
    BAR();

    // ---- P1: read b1; issue A(t+2)q0 -----------------------------------
#pragma unroll
    for (int nf = 0; nf < 2; ++nf) {
      const int st = 128 + wid_n * 32 + nf * 16 + lr;
      b1[nf][0] = *(const bf16x8*)(LB + st * 128 + ((0 + lq) ^ bxn[nf]) * 16);
      b1[nf][1] = *(const bf16x8*)(LB + st * 128 + ((4 + lq) ^ bxn[nf]) * 16);
    }
    stageA(cur, 0, t2v);
    SB0();
    BAR();
    WAITLGKM(); SB0();
    __builtin_amdgcn_s_setprio(1);
#pragma unroll
    for (int mf = 0; mf < 4; ++mf)
#pragma unroll
      for (int nf = 0; nf < 2; ++nf) {
        acc[mf][2 + nf] = __builtin_amdgcn_mfma_f32_16x16x32_bf16(a[mf][0], b1[nf][0], acc[mf][2 + nf], 0, 0, 0);
        acc[mf][2 + nf] = __builtin_amdgcn_mfma_f32_16x16x32_bf16(a[mf][1], b1[nf][1], acc[mf][2 + nf], 0, 0, 0);
      }
    __builtin_amdgcn_s_setprio(0);
    BAR();

    // ---- P2: read a(q1); vmcnt(4) -> write B(t+1); issue B(t+2) --------
#pragma unroll
    for (int mf = 0; mf < 4; ++mf) {
      const int st = 128 + wid_m * 64 + mf * 16 + lr;
      a[mf][0] = *(const bf16x8*)(LA + st * 128 + axA0);
      a[mf][1] = *(const bf16x8*)(LA + st * 128 + axA1);
    }
    SB0();
    WAITVM(4); SB0();          // B(t+1) regs ready (leaves Aq1(t+1), Aq0(t+2))
    WRITEB(bo);
    WAITLGKM(); SB0();         // drain a(q1) reads + B writes (WAR on bv)
    LOADB(t2v);                // 8 f4  B(t+2)
    SB0();
    BAR();
    __builtin_amdgcn_s_setprio(1);
#pragma unroll
    for (int mf = 0; mf < 4; ++mf)
#pragma unroll
      for (int nf = 0; nf < 2; ++nf) {
        acc[4 + mf][2 + nf] = __builtin_amdgcn_mfma_f32_16x16x32_bf16(a[mf][0], b1[nf][0], acc[4 + mf][2 + nf], 0, 0, 0);
        acc[4 + mf][2 + nf] = __builtin_amdgcn_mfma_f32_16x16x32_bf16(a[mf][1], b1[nf][1], acc[4 + mf][2 + nf], 0, 0, 0);
      }
    __builtin_amdgcn_s_setprio(0);
    BAR();

    // ---- P3: issue A(t+2)q1; vmcnt(12); MFMA on regs -------------------
    stageA(cur, 1, t2v);
    SB0();
    WAITVM(12); SB0();         // drain Aq1(t+1) (read next tile P2)
    BAR();
    __builtin_amdgcn_s_setprio(1);
#pragma unroll
    for (int mf = 0; mf < 4; ++mf)
#pragma unroll
      for (int nf = 0; nf < 2; ++nf) {
        acc[4 + mf][nf] = __builtin_amdgcn_mfma_f32_16x16x32_bf16(a[mf][0], b0[nf][0], acc[4 + mf][nf], 0, 0, 0);
        acc[4 + mf][nf] = __builtin_amdgcn_mfma_f32_16x16x32_bf16(a[mf][1], b0[nf][1], acc[4 + mf][nf], 0, 0, 0);
      }
    __builtin_amdgcn_s_setprio(0);
    BAR();
  }

  WAITVM(0);                   // trailing clamped loads must not outlive LDS

  // ---------------- epilogue (C/D: col=lane&15, row=(lane>>4)*4+r) -------
  if (OUTBF) {
    unsigned short* Cc = (unsigned short*)Cout + (long)e * sC;
#pragma unroll
    for (int mf = 0; mf < 8; ++mf)
#pragma unroll
      for (int q = 0; q < 4; ++q)
#pragma unroll
        for (int rr = 0; rr < 4; ++rr) {
          const int row = mb * 256 + wid_m * 128 + mf * 16 + lq * 4 + rr;
          const int col = nb * 256 + wid_n * 64 + q * 16 + lr;
          Cc[(long)row * LDC + col] = f2bf(acc[mf][q][rr]);
        }
  } else {
    float* Cc = (float*)Cout + (long)e * sC;
#pragma unroll
    for (int mf = 0; mf < 8; ++mf)
#pragma unroll
      for (int q = 0; q < 4; ++q)
#pragma unroll
        for (int rr = 0; rr < 4; ++rr) {
          const int row = mb * 256 + wid_m * 128 + mf * 16 + lq * 4 + rr;
          const int col = nb * 256 + wid_n * 64 + q * 16 + lr;
          Cc[(long)row * LDC + col] = acc[mf][q][rr];
        }
  }
}

// ---------------------------------------------------------------------------
extern "C" void kernel_launch(void* const* d_in, const int* in_sizes, int n_in,
                              void* d_out, int out_size, void* d_ws, size_t ws_size,
                              hipStream_t stream) {
  const float* hs = (const float*)d_in[0];   // (8192, 2048)
  const float* w1 = (const float*)d_in[1];   // (8, 2048, 8192)
  const float* w2 = (const float*)d_in[2];   // (8, 4096, 2048)
  float* out = (float*)d_out;                // (8192, 2048) fp32
  char* ws = (char*)d_ws;

  const long HB_B  = (long)T_ * H_ * 2;          //  32 MiB hidden bf16
  const long ACT_B = (long)T_ * I_ * 2;          //  64 MiB acted bf16
  const long GU_B  = (long)T_ * 2 * I_ * 2;      // 128 MiB gate_up bf16
  if (ws_size < (size_t)(HB_B + ACT_B + GU_B)) return;

  unsigned short* hiddenB = (unsigned short*)(ws);
  unsigned short* acted   = (unsigned short*)(ws + HB_B);
  unsigned short* gate_up = (unsigned short*)(ws + HB_B + ACT_B);

  hipLaunchKernelGGL(convert_bf16, dim3(2048), dim3(256), 0, stream,
                     hs, hiddenB, (long)T_ * H_);

  // gemm1 (plain): A=hiddenB (TPE,H), B=W1 (H,2I) fp32 -> gate_up bf16
  hipLaunchKernelGGL((gemm_fused<H_, 32, 2 * I_, 2 * I_, true>),
                     dim3(1024), dim3(512), 131072, stream,
                     hiddenB, w1, gate_up,
                     (long)TPE * H_, (long)H_ * 2 * I_, (long)TPE * 2 * I_);

  // acted = up * silu(gate)
  hipLaunchKernelGGL(silu_mul, dim3(2048), dim3(256), 0, stream,
                     gate_up, acted, (long)T_ * I_ / 8);

  // gemm2: A=acted (TPE,I), B=W2 (I,H) fp32 -> out fp32
  hipLaunchKernelGGL((gemm_fused<I_, 8, H_, H_, false>),
                     dim3(256), dim3(512), 131072, stream,
                     acted, w2, out,
                     (long)TPE * I_, (long)I_ * H_, (long)TPE * H_);
}